// Round 9
// baseline (174.279 us; speedup 1.0000x reference)
//
#include <hip/hip_runtime.h>

#define NN 4096
#define F_IN 1024
#define NHEAD 8
#define HID 64
#define NCLS 40
#define LOG2E 1.44269504f

typedef float f32x4 __attribute__((ext_vector_type(4)));
typedef float f32x2 __attribute__((ext_vector_type(2)));
typedef short s16x8 __attribute__((ext_vector_type(8)));

// XOR-swizzled halfword index within a [R][64]-hw (128B-row) LDS tile:
// byte ^= (row&7)<<4  ->  halfword col ^= (row&7)<<3. 16B-chunk bijective per row.
#define SWZ(r,c) (((r)*64) + ((c) ^ (((r)&7)<<3)))

__device__ __forceinline__ unsigned short f2bf(float f){  // RNE float->bf16
  unsigned u = __float_as_uint(f);
  return (unsigned short)((u + 0x7fffu + ((u >> 16) & 1u)) >> 16);
}
__device__ __forceinline__ unsigned cvtpk(float lo, float hi){  // packed bf16 pair
  unsigned r; asm("v_cvt_pk_bf16_f32 %0, %1, %2" : "=v"(r) : "v"(lo), "v"(hi)); return r;
}
__device__ __forceinline__ f32x2 pkmul(f32x2 a, f32x2 b){  // packed fp32 dual mul
  f32x2 r; asm("v_pk_mul_f32 %0, %1, %2" : "=v"(r) : "v"(a), "v"(b)); return r;
}

// ---------------- pack adjacency -> word-transposed bitmask ----------------
__global__ __launch_bounds__(256) void pack_adj_k(const int* __restrict__ adj, unsigned* __restrict__ bmT){
  int gid = blockIdx.x*256 + threadIdx.x;
  int lane = threadIdx.x & 63;
  unsigned long long m = __ballot(adj[gid] > 0);
  int w = gid >> 5, i = w >> 7, jw = w & 127;
  if (lane == 0)       bmT[(size_t)jw*NN + i] = (unsigned)m;
  else if (lane == 32) bmT[(size_t)jw*NN + i] = (unsigned)(m >> 32);
}

// ---------------- WbT[h][o][k] = bf16(W[h][k][o]) ----------------
__global__ __launch_bounds__(256) void cast_W_k(const float* __restrict__ W, unsigned short* __restrict__ WbT){
  __shared__ float T[64][65];
  const int h = blockIdx.y, k0 = blockIdx.x*64, t = threadIdx.x;
  for (int idx = t; idx < 1024; idx += 256){
    int k = idx >> 4, c4 = idx & 15;
    *(float4*)&T[k][c4*4] = *(const float4*)&W[((size_t)h*F_IN + k0 + k)*HID + c4*4];
  }
  __syncthreads();
  for (int idx = t; idx < 512; idx += 256){
    int o = idx >> 3, ch = idx & 7;
    s16x8 v;
    #pragma unroll
    for (int e = 0; e < 8; ++e) v[e] = (short)f2bf(T[ch*8 + e][o]);
    *(s16x8*)&WbT[((size_t)h*HID + o)*F_IN + k0 + ch*8] = v;
  }
}

// ---------------- WoT[c][k] = bf16(W_out[k][c]), rows 40..47 zero ----------------
__global__ __launch_bounds__(256) void cast_Wo_k(const float* __restrict__ Wout, unsigned short* __restrict__ WoT){
  int idx = blockIdx.x*256 + threadIdx.x;   // 48*512
  int cc = idx >> 9, k = idx & 511;
  WoT[idx] = (cc < NCLS) ? f2bf(Wout[(size_t)k*NCLS + cc]) : (unsigned short)0;
}

// ---------------- gemm1: WhT[h][o][n] bf16 = (x@W)^T ; srcv/dstv fused epilogue ----------------
__global__ __launch_bounds__(256) void gemm1_k(const float* __restrict__ x,
    const unsigned short* __restrict__ WbT, unsigned short* __restrict__ WhT,
    const float* __restrict__ a_src, const float* __restrict__ a_dst,
    float* __restrict__ srcv, float* __restrict__ dstv){
  __shared__ unsigned short xS[64*64];
  __shared__ unsigned short wS[64*64];
  const int t = threadIdx.x, l = t & 63, wv = t >> 6, g = l >> 4, c = l & 15;
  const int h = blockIdx.y, n0 = blockIdx.x * 64;
  f32x4 acc[4] = {};
  for (int k0 = 0; k0 < F_IN; k0 += 64){
    __syncthreads();
    #pragma unroll
    for (int p = 0; p < 4; ++p){
      int idx = t + p*256, row = idx >> 4, c4 = idx & 15;
      float4 v = *(const float4*)&x[(size_t)(n0+row)*F_IN + k0 + c4*4];
      *(uint2*)&xS[SWZ(row, c4*4)] = make_uint2(cvtpk(v.x, v.y), cvtpk(v.z, v.w));
    }
    #pragma unroll
    for (int p = 0; p < 2; ++p){
      int idx = t + p*256, o = idx >> 3, ch = idx & 7;
      *(s16x8*)&wS[SWZ(o, ch*8)] = *(const s16x8*)&WbT[(size_t)(h*HID + o)*F_IN + k0 + ch*8];
    }
    __syncthreads();
    #pragma unroll
    for (int ks = 0; ks < 2; ++ks){
      s16x8 av = *(const s16x8*)&xS[SWZ(wv*16 + c, ks*32 + g*8)];
      #pragma unroll
      for (int ct = 0; ct < 4; ++ct){
        s16x8 bv = *(const s16x8*)&wS[SWZ(ct*16 + c, ks*32 + g*8)];
        acc[ct] = __builtin_amdgcn_mfma_f32_16x16x32_bf16(av, bv, acc[ct], 0, 0, 0);
      }
    }
  }
  float asv[4], adv[4];
  #pragma unroll
  for (int ct = 0; ct < 4; ++ct){ asv[ct] = a_src[h*HID + ct*16 + c]; adv[ct] = a_dst[h*HID + ct*16 + c]; }
  #pragma unroll
  for (int r = 0; r < 4; ++r){
    float ps = acc[0][r]*asv[0] + acc[1][r]*asv[1] + acc[2][r]*asv[2] + acc[3][r]*asv[3];
    float pd = acc[0][r]*adv[0] + acc[1][r]*adv[1] + acc[2][r]*adv[2] + acc[3][r]*adv[3];
    #pragma unroll
    for (int off = 1; off < 16; off <<= 1){ ps += __shfl_xor(ps, off); pd += __shfl_xor(pd, off); }
    if (c == 0){ int n = n0 + wv*16 + g*4 + r; srcv[h*NN + n] = ps; dstv[h*NN + n] = pd; }
  }
  __syncthreads();
  #pragma unroll
  for (int ct = 0; ct < 4; ++ct)
    *(uint2*)&xS[SWZ(ct*16 + c, wv*16 + g*4)] = make_uint2(cvtpk(acc[ct][0], acc[ct][1]), cvtpk(acc[ct][2], acc[ct][3]));
  __syncthreads();
  #pragma unroll
  for (int p = 0; p < 2; ++p){
    int idx = t + p*256, o = idx >> 3, ch = idx & 7;
    *(s16x8*)&WhT[(size_t)(h*HID + o)*NN + n0 + ch*8] = *(const s16x8*)&xS[SWZ(o, ch*8)];
  }
}

// ---------------- per-4096-segment max reduce ----------------
__global__ __launch_bounds__(256) void maxred_k(const float* __restrict__ in, float* __restrict__ out){
  __shared__ float red[4];
  const float* p = in + (size_t)blockIdx.x*NN;
  float m = -3.0e38f;
  for (int i = threadIdx.x; i < NN; i += 256) m = fmaxf(m, p[i]);
  #pragma unroll
  for (int off = 32; off; off >>= 1) m = fmaxf(m, __shfl_xor(m, off));
  if ((threadIdx.x & 63) == 0) red[threadIdx.x >> 6] = m;
  __syncthreads();
  if (threadIdx.x == 0) out[blockIdx.x] = fmaxf(fmaxf(red[0], red[1]), fmaxf(red[2], red[3]));
}

// ---------------- MFMA masked-softmax aggregate v2 ----------------
// Block: 64 rows x one head. 4 waves = 4 j-parities, barrier-free j-loop.
// Each wave: 4 A-frags (all 64 rows) x NCT V-frags; V read DIRECTLY from global (L2-resident),
// each bv feeds 4 MFMAs. dS/bitS wave-private (parity dbuf) with lgkmcnt(0) visibility.
// p_ij = bit * med3(A_i*B_j, C_i*D_j, 1). Row sums via ones-MFMA. 2-round merge; wave w owns rows w*16..
template<int NCT, int NJT, bool CHUNKED, bool DO_ELU>
__global__ __launch_bounds__(256) void agg_mfma_k(
    const unsigned* __restrict__ bmT, const unsigned short* __restrict__ VT,
    const float* __restrict__ srcv, const float* __restrict__ dstv,
    const float* __restrict__ maxp, void* __restrict__ outp)
{
  __shared__ float2 dS[4][2][64];          // [wave][parity][j]   (B_j, D_j)
  __shared__ unsigned bitS[4][2][2][64];   // [wave][parity][jword][row]
  __shared__ float mrg[2][3][16][NCT*16 + 4];
  const int t = threadIdx.x, l = t & 63, wv = t >> 6, g = l >> 4, c = l & 15;
  const int h   = CHUNKED ? 0 : blockIdx.y;
  const int jt0 = CHUNKED ? blockIdx.y * NJT : 0;
  const int i0 = blockIdx.x * 64;
  const float mx = maxp[CHUNKED ? 0 : h];
  f32x2 ac2[4];
  #pragma unroll
  for (int af = 0; af < 4; ++af){
    float sr = srcv[h*NN + i0 + af*16 + c];
    float tm = sr + mx;
    float mi2 = fmaxf(tm, 0.2f*tm) * LOG2E;
    ac2[af][0] = exp2f(fmaf(sr, LOG2E, -mi2));        // A_i
    ac2[af][1] = exp2f(fmaf(0.2f*sr, LOG2E, -mi2));   // C_i
  }
  const unsigned short* vb = VT + (CHUNKED ? (size_t)0 : (size_t)h*HID*NN);
  const float* dp = dstv + (size_t)h*NN;

  f32x4 acc[4][NCT] = {};
  f32x4 accs[4] = {};
  s16x8 ones;
  #pragma unroll
  for (int e = 0; e < 8; ++e) ones[e] = (short)0x3F80;

  // prefetch first tile scalars
  float dcur = dp[(jt0 + wv)*64 + l];
  unsigned b0 = bmT[(size_t)((jt0 + wv)*2 + 0)*NN + i0 + l];
  unsigned b1 = bmT[(size_t)((jt0 + wv)*2 + 1)*NN + i0 + l];
  int pp = 0;
  for (int jt = jt0 + wv; jt < jt0 + NJT; jt += 4){
    // stage current tile's (B,D) + bits into wave-private LDS
    dS[wv][pp][l] = make_float2(exp2f(dcur*LOG2E), exp2f(0.2f*dcur*LOG2E));
    bitS[wv][pp][0][l] = b0;
    bitS[wv][pp][1][l] = b1;
    // prefetch next tile scalars
    if (jt + 4 < jt0 + NJT){
      dcur = dp[(jt+4)*64 + l];
      b0 = bmT[(size_t)((jt+4)*2 + 0)*NN + i0 + l];
      b1 = bmT[(size_t)((jt+4)*2 + 1)*NN + i0 + l];
    }
    // V fragments straight from global (L2): perfect 64B-line coalescing
    s16x8 bv[2][NCT];
    #pragma unroll
    for (int ks = 0; ks < 2; ++ks)
      #pragma unroll
      for (int ct = 0; ct < NCT; ++ct)
        bv[ks][ct] = *(const s16x8*)&vb[(size_t)(ct*16 + c)*NN + jt*64 + ks*32 + g*8];
    asm volatile("s_waitcnt lgkmcnt(0)" ::: "memory");   // wave-internal LDS visibility
    #pragma unroll
    for (int ks = 0; ks < 2; ++ks){
      f32x2 drv[8];
      #pragma unroll
      for (int e = 0; e < 8; ++e) drv[e] = *(const f32x2*)&dS[wv][pp][ks*32 + g*8 + e];
      #pragma unroll
      for (int af = 0; af < 4; ++af){
        unsigned wb = (bitS[wv][pp][ks][af*16 + c] >> (g*8)) & 0xffu;
        float q[8];
        #pragma unroll
        for (int e = 0; e < 8; ++e){
          f32x2 pr = pkmul(ac2[af], drv[e]);
          float m3 = __builtin_amdgcn_fmed3f(pr[0], pr[1], 1.0f);
          q[e] = (wb & (1u << e)) ? m3 : 0.f;
        }
        s16x8 afr;
        ((unsigned*)&afr)[0] = cvtpk(q[0], q[1]);
        ((unsigned*)&afr)[1] = cvtpk(q[2], q[3]);
        ((unsigned*)&afr)[2] = cvtpk(q[4], q[5]);
        ((unsigned*)&afr)[3] = cvtpk(q[6], q[7]);
        #pragma unroll
        for (int ct = 0; ct < NCT; ++ct)
          acc[af][ct] = __builtin_amdgcn_mfma_f32_16x16x32_bf16(afr, bv[ks][ct], acc[af][ct], 0, 0, 0);
        accs[af] = __builtin_amdgcn_mfma_f32_16x16x32_bf16(afr, ones, accs[af], 0, 0, 0);
      }
    }
    pp ^= 1;
  }

  // 2-round merge: round q2 merges row-groups {2q2, 2q2+1}; wave w ends owning af == w
  __syncthreads();
  #pragma unroll
  for (int q2 = 0; q2 < 2; ++q2){
    #pragma unroll
    for (int af2 = 0; af2 < 2; ++af2){
      int af = 2*q2 + af2;
      if (wv != af){
        int s = wv - (wv > af ? 1 : 0);
        #pragma unroll
        for (int ct = 0; ct < NCT; ++ct)
          #pragma unroll
          for (int r = 0; r < 4; ++r)
            mrg[af2][s][g*4+r][ct*16+c] = acc[af][ct][r];
        if (c == 0){
          #pragma unroll
          for (int r = 0; r < 4; ++r) mrg[af2][s][g*4+r][NCT*16] = accs[af][r];
        }
      }
    }
    __syncthreads();
    if ((wv >> 1) == q2){
      int af = wv, af2 = wv & 1;
      #pragma unroll
      for (int ct = 0; ct < NCT; ++ct)
        #pragma unroll
        for (int r = 0; r < 4; ++r)
          acc[af][ct][r] += mrg[af2][0][g*4+r][ct*16+c] + mrg[af2][1][g*4+r][ct*16+c] + mrg[af2][2][g*4+r][ct*16+c];
      #pragma unroll
      for (int r = 0; r < 4; ++r)
        accs[af][r] += mrg[af2][0][g*4+r][NCT*16] + mrg[af2][1][g*4+r][NCT*16] + mrg[af2][2][g*4+r][NCT*16];
    }
    __syncthreads();
  }

  // epilogue: wave wv writes rows i0 + wv*16 + g*4 + r
  if (!CHUNKED){
    unsigned short* ob = (unsigned short*)outp;
    #pragma unroll
    for (int r = 0; r < 4; ++r){
      float inv = 1.f / fmaxf(accs[wv][r], 1e-30f);
      int row = i0 + wv*16 + g*4 + r;
      #pragma unroll
      for (int ct = 0; ct < NCT; ++ct){
        float v = acc[wv][ct][r] * inv;
        if (DO_ELU) v = v > 0.f ? v : __expf(v) - 1.f;
        ob[(size_t)row*(NHEAD*HID) + h*HID + ct*16 + c] = f2bf(v);
      }
    }
  } else {
    float* ob = (float*)outp + (size_t)blockIdx.y * NN * 64;
    #pragma unroll
    for (int r = 0; r < 4; ++r){
      int row = i0 + wv*16 + g*4 + r;
      #pragma unroll
      for (int ct = 0; ct < NCT; ++ct)
        ob[(size_t)row*64 + ct*16 + c] = acc[wv][ct][r];
      if (c == 0) ob[(size_t)row*64 + 48] = accs[wv][r];
    }
  }
}

// ---------------- gemm2: WhT2[c][n] bf16 = (h_bf16 @ W_out)^T ; s2/d2 fused ----------------
__global__ __launch_bounds__(256) void gemm2_k(const unsigned short* __restrict__ hb,
    const unsigned short* __restrict__ WoT, const float* __restrict__ aos, const float* __restrict__ aod,
    unsigned short* __restrict__ WhT2, float* __restrict__ s2, float* __restrict__ d2){
  __shared__ unsigned short aS[64*64];
  __shared__ unsigned short bS[48*64];
  const int t = threadIdx.x, l = t & 63, wv = t >> 6, g = l >> 4, c = l & 15;
  const int n0 = blockIdx.x * 64;
  f32x4 acc[3] = {};
  for (int k0 = 0; k0 < NHEAD*HID; k0 += 64){
    __syncthreads();
    #pragma unroll
    for (int p = 0; p < 2; ++p){
      int u = t + p*256, o = u >> 3, ch = u & 7;
      *(s16x8*)&aS[SWZ(o, ch*8)] = *(const s16x8*)&hb[(size_t)(n0+o)*(NHEAD*HID) + k0 + ch*8];
    }
    for (int u = t; u < 384; u += 256){
      int o = u >> 3, ch = u & 7;
      *(s16x8*)&bS[SWZ(o, ch*8)] = *(const s16x8*)&WoT[(size_t)o*(NHEAD*HID) + k0 + ch*8];
    }
    __syncthreads();
    #pragma unroll
    for (int ks = 0; ks < 2; ++ks){
      s16x8 av = *(const s16x8*)&aS[SWZ(wv*16 + c, ks*32 + g*8)];
      #pragma unroll
      for (int ct = 0; ct < 3; ++ct){
        s16x8 bv = *(const s16x8*)&bS[SWZ(ct*16 + c, ks*32 + g*8)];
        acc[ct] = __builtin_amdgcn_mfma_f32_16x16x32_bf16(av, bv, acc[ct], 0, 0, 0);
      }
    }
  }
  float asv[3], adv[3];
  #pragma unroll
  for (int ct = 0; ct < 3; ++ct){
    int col = ct*16 + c;
    asv[ct] = (col < NCLS) ? aos[col] : 0.f;
    adv[ct] = (col < NCLS) ? aod[col] : 0.f;
  }
  #pragma unroll
  for (int r = 0; r < 4; ++r){
    float ps = acc[0][r]*asv[0] + acc[1][r]*asv[1] + acc[2][r]*asv[2];
    float pd = acc[0][r]*adv[0] + acc[1][r]*adv[1] + acc[2][r]*adv[2];
    #pragma unroll
    for (int off = 1; off < 16; off <<= 1){ ps += __shfl_xor(ps, off); pd += __shfl_xor(pd, off); }
    if (c == 0){ int n = n0 + wv*16 + g*4 + r; s2[n] = ps; d2[n] = pd; }
  }
  __syncthreads();
  #pragma unroll
  for (int ct = 0; ct < 3; ++ct)
    *(uint2*)&bS[SWZ(ct*16 + c, wv*16 + g*4)] = make_uint2(cvtpk(acc[ct][0], acc[ct][1]), cvtpk(acc[ct][2], acc[ct][3]));
  __syncthreads();
  for (int u = t; u < 384; u += 256){
    int o = u >> 3, ch = u & 7;
    *(s16x8*)&WhT2[(size_t)o*NN + n0 + ch*8] = *(const s16x8*)&bS[SWZ(o, ch*8)];
  }
}

// ---------------- merge 8 chunks + elu + row log_softmax ----------------
__global__ __launch_bounds__(256) void final_k(const float* __restrict__ part, float* __restrict__ out){
  const int wid = (blockIdx.x*256 + threadIdx.x) >> 6;
  const int c = threadIdx.x & 63;
  float acc = 0.f, rs = 0.f;
  #pragma unroll
  for (int ch = 0; ch < 8; ++ch){
    const float* pb = part + ((size_t)ch*NN + wid)*64;
    if (c < 48) acc += pb[c];
    rs += pb[48];
  }
  float v = acc / fmaxf(rs, 1e-30f);
  float e = v > 0.f ? v : __expf(v) - 1.f;
  float ev = (c < NCLS) ? e : -3.0e38f;
  float m = ev;
  #pragma unroll
  for (int off = 32; off; off >>= 1) m = fmaxf(m, __shfl_xor(m, off));
  float ex = (c < NCLS) ? __expf(e - m) : 0.f;
  float s = ex;
  #pragma unroll
  for (int off = 32; off; off >>= 1) s += __shfl_xor(s, off);
  if (c < NCLS) out[(size_t)wid*NCLS + c] = e - m - __logf(s);
}

extern "C" void kernel_launch(void* const* d_in, const int* in_sizes, int n_in,
                              void* d_out, int out_size, void* d_ws, size_t ws_size,
                              hipStream_t stream){
  (void)in_sizes; (void)n_in; (void)out_size; (void)ws_size;
  const float* x     = (const float*)d_in[0];
  const int*   adj   = (const int*)  d_in[1];
  const float* W     = (const float*)d_in[2];
  const float* a_src = (const float*)d_in[3];
  const float* a_dst = (const float*)d_in[4];
  const float* W_out = (const float*)d_in[5];
  const float* aos   = (const float*)d_in[6];
  const float* aod   = (const float*)d_in[7];
  float* out = (float*)d_out;

  char* p = (char*)d_ws;
  unsigned* bmT        = (unsigned*)p;       p += (size_t)NN*128*4;            // 2 MB
  unsigned short* WbT  = (unsigned short*)p; p += (size_t)NHEAD*HID*F_IN*2;    // 1 MB
  unsigned short* WhT  = (unsigned short*)p; p += (size_t)NHEAD*HID*NN*2;      // 4 MB
  unsigned short* hbuf = (unsigned short*)p; p += (size_t)NN*NHEAD*HID*2;      // 4 MB
  unsigned short* WoT  = (unsigned short*)p; p += (size_t)48*NHEAD*HID*2;      // 48 KB
  unsigned short* WhT2 = (unsigned short*)p; p += (size_t)48*NN*2;             // 384 KB
  float* srcv = (float*)p; p += (size_t)NHEAD*NN*4;
  float* dstv = (float*)p; p += (size_t)NHEAD*NN*4;
  float* maxd = (float*)p; p += 256;
  float* s2   = (float*)p; p += (size_t)NN*4;
  float* d2   = (float*)p; p += (size_t)NN*4;
  float* m2   = (float*)p; p += 256;
  float* part = (float*)p; p += (size_t)8*NN*64*4;                             // 8 MB

  pack_adj_k<<<(NN*NN)/256, 256, 0, stream>>>(adj, bmT);
  cast_W_k<<<dim3(F_IN/64, NHEAD), 256, 0, stream>>>(W, WbT);
  cast_Wo_k<<<96, 256, 0, stream>>>(W_out, WoT);
  gemm1_k<<<dim3(NN/64, NHEAD), 256, 0, stream>>>(x, WbT, WhT, a_src, a_dst, srcv, dstv);
  maxred_k<<<NHEAD, 256, 0, stream>>>(dstv, maxd);
  agg_mfma_k<4, 64, false, true><<<dim3(NN/64, NHEAD), 256, 0, stream>>>(bmT, WhT, srcv, dstv, maxd, hbuf);
  gemm2_k<<<NN/64, 256, 0, stream>>>(hbuf, WoT, aos, aod, WhT2, s2, d2);
  maxred_k<<<1, 256, 0, stream>>>(d2, m2);
  agg_mfma_k<3, 8, true, false><<<dim3(NN/64, 8), 256, 0, stream>>>(bmT, WhT2, s2, d2, m2, part);
  final_k<<<NN/4, 256, 0, stream>>>(part, out);
}